// Round 3
// baseline (63.001 us; speedup 1.0000x reference)
//
#include <hip/hip_runtime.h>
#include <math.h>

#define LNUM 6
#define BNUM 8
#define NNUM 300
#define CNUM 20
#define HW   784
#define HW4  196   // HW/4
#define GH   448
#define NW   16    // mask words per (b,n): permuted bit order (popcount-invariant)
#define AW   5     // adjacency row words (300 bits -> 5 x u64)
#define RTILE 16   // rows per bce tile
#define NTILE 28   // 448/16 tiles per (b,c)

// ---- device scratch (recomputed every launch; no cross-launch state) ----
__device__ float              g_rm [BNUM*NNUM*HW];
__device__ unsigned long long g_T  [BNUM*NNUM*NW];
__device__ int                g_s  [BNUM*NNUM];
__device__ unsigned long long g_adj[BNUM*NNUM*AW];
__device__ float              g_mm [BNUM*CNUM*HW];
__device__ double             g_part[BNUM*CNUM*NTILE];  // written by active blocks only

// One block per (b,n): mean over L (float4), relu, max-normalize, rm + bitmask + popcount.
// Bit order within g_T is a fixed permutation of pixels; only popcounts are consumed.
__global__ void k_rm(const float* __restrict__ sm) {
    int bn  = blockIdx.x;
    int tid = threadIdx.x;               // 256
    int lane = tid & 63, wid = tid >> 6;
    __shared__ float wmax[4];
    __shared__ int   scount;
    if (tid == 0) scount = 0;
    const size_t lstr4 = (size_t)BNUM * NNUM * HW4;   // float4 stride per l
    const float4* base = (const float4*)sm + (size_t)bn * HW4;
    bool act = tid < HW4;
    float4 v = {0.f, 0.f, 0.f, 0.f};
    if (act) {
        float4 a = {0.f, 0.f, 0.f, 0.f};
        #pragma unroll
        for (int l = 0; l < LNUM; ++l) {
            float4 x = base[(size_t)l * lstr4 + tid];
            a.x += x.x; a.y += x.y; a.z += x.z; a.w += x.w;
        }
        v.x = fmaxf(__fdiv_rn(a.x, 6.0f), 0.0f);
        v.y = fmaxf(__fdiv_rn(a.y, 6.0f), 0.0f);
        v.z = fmaxf(__fdiv_rn(a.z, 6.0f), 0.0f);
        v.w = fmaxf(__fdiv_rn(a.w, 6.0f), 0.0f);
    }
    float lm = fmaxf(fmaxf(v.x, v.y), fmaxf(v.z, v.w));
    #pragma unroll
    for (int off = 32; off; off >>= 1) lm = fmaxf(lm, __shfl_xor(lm, off));
    if (lane == 0) wmax[wid] = lm;
    __syncthreads();
    float mx = fmaxf(fmaxf(wmax[0], wmax[1]), fmaxf(wmax[2], wmax[3]));
    float d = mx + 1e-6f;
    float4 nv;
    nv.x = __fdiv_rn(v.x, d); nv.y = __fdiv_rn(v.y, d);
    nv.z = __fdiv_rn(v.z, d); nv.w = __fdiv_rn(v.w, d);
    if (act) ((float4*)g_rm)[(size_t)bn * HW4 + tid] = nv;
    float c[4] = {nv.x, nv.y, nv.z, nv.w};
    #pragma unroll
    for (int k = 0; k < 4; ++k) {
        bool pr = act && (c[k] > 0.7f);
        unsigned long long ball = __ballot(pr);
        if (lane == 0) {
            g_T[(size_t)bn * NW + k * 4 + wid] = ball;
            atomicAdd(&scount, __popcll(ball));
        }
    }
    __syncthreads();
    if (tid == 0) g_s[bn] = scount;
}

// One block per (b,i): adjacency row i via popcount(AND) + exact f32 (iou+dice)/2 > 0.5
__global__ void k_adj() {
    int blk = blockIdx.x;                // b*300 + i
    int b = blk / NNUM;
    int tid = threadIdx.x;               // 320 (5 waves)
    __shared__ unsigned long long Ti[NW];
    __shared__ int si_sh;
    if (tid < NW)  Ti[tid] = g_T[(size_t)blk * NW + tid];
    if (tid == NW) si_sh = g_s[blk];
    __syncthreads();
    bool a = false;
    int j = tid;
    if (j < NNUM) {
        const unsigned long long* Tj = &g_T[((size_t)b * NNUM + j) * NW];
        int inter = 0;
        #pragma unroll
        for (int w = 0; w < NW; ++w) inter += __popcll(Ti[w] & Tj[w]);
        int si = si_sh, sj = g_s[b * NNUM + j];
        int uni = si + sj - inter, tot = si + sj;
        float iou  = (uni == 0) ? 1.0f : __fdiv_rn((float)inter, (float)uni);
        float dice = (tot == 0) ? 1.0f : __fdiv_rn(2.0f * (float)inter, (float)tot);
        a = (0.5f * (iou + dice)) > 0.5f;
    }
    unsigned long long ball = __ballot(a);
    if ((tid & 63) == 0) g_adj[(size_t)blk * AW + (tid >> 6)] = ball;
}

// One block per active (b,c): cluster (wave 0) + meanmap (all 4 waves), fused.
__global__ void k_cm(const float* __restrict__ score, const int* __restrict__ label) {
    int blk = blockIdx.x;                // b*C + c
    if (label[blk] == 0) return;         // uniform across block, before any barrier
    int b = blk / CNUM, c = blk - b * CNUM;
    int tid = threadIdx.x;               // 256
    int lane = tid & 63, wid = tid >> 6;
    __shared__ unsigned long long adj_sh[NNUM][AW];
    __shared__ unsigned long long cand[AW], fin[AW], nwv[AW];
    __shared__ int sh_has, sh_go;
    __shared__ float sh_cf;
    for (int idx = tid; idx < NNUM * AW; idx += 256)
        ((unsigned long long*)adj_sh)[idx] = g_adj[(size_t)b * NNUM * AW + idx];
    if (wid == 0) {
        // cand bits + masked/unmasked first-argmax
        float bv = -INFINITY; int bi = NNUM;
        float bva = -INFINITY; int bia = NNUM;
        for (int k = 0; k < AW; ++k) {
            int j = k * 64 + lane;
            bool cb = false;
            if (j < NNUM) {
                float sc = score[((size_t)b * NNUM + j) * CNUM + c];
                if (sc > bva) { bva = sc; bia = j; }   // strict > keeps first occurrence
                cb = sc > 0.01f;
                if (cb && sc > bv) { bv = sc; bi = j; }
            }
            unsigned long long ball = __ballot(cb);
            if (lane == 0) cand[k] = ball;
        }
        #pragma unroll
        for (int off = 1; off < 64; off <<= 1) {
            float ov = __shfl_xor(bv, off);  int oi = __shfl_xor(bi, off);
            if (ov > bv || (ov == bv && oi < bi)) { bv = ov; bi = oi; }
            float ova = __shfl_xor(bva, off); int oia = __shfl_xor(bia, off);
            if (ova > bva || (ova == bva && oia < bia)) { bva = ova; bia = oia; }
        }
        bool has = (cand[0] | cand[1] | cand[2] | cand[3] | cand[4]) != 0ULL;
        if (lane == 0) sh_has = has ? 1 : 0;
        if (has) {
            if (lane < AW) fin[lane] = cand[lane] & adj_sh[bi][lane];
        } else {
            if (lane < AW) fin[lane] = ((bia >> 6) == lane) ? (1ULL << (bia & 63)) : 0ULL;
        }
    }
    __syncthreads();
    if (sh_has) {
        for (int it = 0; it < NNUM + 2; ++it) {
            if (wid == 0) {
                for (int k = 0; k < AW; ++k) {
                    int j = k * 64 + lane;
                    bool nb = false;
                    if (j < NNUM && ((cand[k] >> lane) & 1ULL)) {
                        unsigned long long o = (adj_sh[j][0] & fin[0]) | (adj_sh[j][1] & fin[1]) |
                                               (adj_sh[j][2] & fin[2]) | (adj_sh[j][3] & fin[3]) |
                                               (adj_sh[j][4] & fin[4]);
                        nb = (o != 0ULL);    // adj symmetric: row j == column j
                    }
                    unsigned long long ball = __ballot(nb);
                    if (lane == 0) nwv[k] = ball;
                }
                bool ch = (lane < AW) && (nwv[lane] != fin[lane]);
                unsigned long long chb = __ballot(ch);
                if (lane == 0) sh_go = (chb != 0ULL) ? 1 : 0;
                if (lane < AW) fin[lane] = nwv[lane];
            }
            __syncthreads();
            int go = sh_go;
            __syncthreads();             // all read sh_go before wave 0 rewrites it
            if (!go) break;
        }
    }
    if (tid == 0) {
        int cs = 0;
        for (int w = 0; w < AW; ++w) cs += __popcll(fin[w]);
        sh_cf = (float)cs;
    }
    __syncthreads();
    // ---- meanmap: float4 accumulation over selected rows ----
    if (tid < HW4) {
        float4 a = {0.f, 0.f, 0.f, 0.f};
        for (int w = 0; w < AW; ++w) {
            unsigned long long word = fin[w];
            while (word) {
                int j = w * 64 + (__ffsll(word) - 1);
                word &= word - 1;
                float4 r = ((const float4*)g_rm)[((size_t)b * NNUM + j) * HW4 + tid];
                a.x += r.x; a.y += r.y; a.z += r.z; a.w += r.w;
            }
        }
        float cc = sh_cf;
        float4 o;
        o.x = __fdiv_rn(a.x, cc); o.y = __fdiv_rn(a.y, cc);
        o.z = __fdiv_rn(a.z, cc); o.w = __fdiv_rn(a.w, cc);
        ((float4*)g_mm)[(size_t)blk * HW4 + tid] = o;
    }
}

// Fused bilinear upsample (28->448, half-pixel, edge clamp) + BCE partial sums.
// 448 threads: thread = (row r in tile, x-strip j). Interior strip j in [0,27):
// 16 px at ox=16j+8 share x0=j; wx=(2k+1)/32 exact. Strip 27 = both edges:
// pred constant per row -> 2 logs per 8 px.
__global__ void k_bce(const int* __restrict__ gt, const int* __restrict__ label) {
    int blk = blockIdx.x;                // bc*NTILE + tile
    int bc = blk / NTILE, tile = blk - bc * NTILE;
    if (label[bc] == 0) return;
    int b = bc / CNUM, c = bc - b * CNUM;
    int tid = threadIdx.x;               // 448 (7 waves)
    __shared__ float m[HW];
    __shared__ float rowY[RTILE * 28];
    __shared__ double wsum[7];
    if (tid < HW4) ((float4*)m)[tid] = ((const float4*)g_mm)[(size_t)bc * HW4 + tid];
    __syncthreads();
    int row0 = tile * RTILE;
    {
        int r = tid / 28, x = tid - r * 28;   // tid < 448 always valid
        int oy = row0 + r;
        float iy = fmaf((float)oy, 0.0625f, -0.46875f);
        float y0f = floorf(iy);
        float wy = iy - y0f;
        int y0 = (int)y0f;
        if (y0 < 0) { y0 = 0; wy = 0.0f; } else if (y0 > 26) { y0 = 26; wy = 1.0f; }
        float lo = m[y0 * 28 + x], hi = m[y0 * 28 + 28 + x];
        rowY[tid] = lo + wy * (hi - lo);
    }
    __syncthreads();
    int r = tid / 28, j = tid - r * 28;
    const int* gr = gt + ((size_t)b * GH + row0 + r) * GH;
    double acc = 0.0;
    int cp1 = c + 1;
    if (j < 27) {
        float rY0 = rowY[r * 28 + j], rY1 = rowY[r * 28 + j + 1];
        float sl = rY1 - rY0;
        const int4* gp = (const int4*)(gr + 16 * j + 8);
        #pragma unroll
        for (int q = 0; q < 4; ++q) {
            int4 g4 = gp[q];
            #pragma unroll
            for (int u = 0; u < 4; ++u) {
                int k = q * 4 + u;
                int gv = (u == 0) ? g4.x : (u == 1) ? g4.y : (u == 2) ? g4.z : g4.w;
                float wk = fmaf((float)k, 0.0625f, 0.03125f);   // (2k+1)/32, exact
                float pred = rY0 + wk * sl;
                float xv = (gv == cp1) ? pred : 1.0f - pred;
                float lg = __logf(fmaxf(xv, 1.175494351e-38f));
                acc += (double)((xv > 0.0f) ? lg : -100.0f);
            }
        }
    } else {
        // left edge ox 0..7: pred = rowY[r][0]; right edge ox 440..447: pred = rowY[r][27]
        #pragma unroll
        for (int side = 0; side < 2; ++side) {
            float pred = rowY[r * 28 + (side ? 27 : 0)];
            const int4* gp = (const int4*)(gr + (side ? 440 : 0));
            int4 a0 = gp[0], a1 = gp[1];
            int np = (a0.x == cp1) + (a0.y == cp1) + (a0.z == cp1) + (a0.w == cp1)
                   + (a1.x == cp1) + (a1.y == cp1) + (a1.z == cp1) + (a1.w == cp1);
            float om = 1.0f - pred;
            float lgp = (pred > 0.0f) ? __logf(fmaxf(pred, 1.175494351e-38f)) : -100.0f;
            float lgn = (om   > 0.0f) ? __logf(fmaxf(om,   1.175494351e-38f)) : -100.0f;
            acc += (double)lgp * (double)np + (double)lgn * (double)(8 - np);
        }
    }
    #pragma unroll
    for (int off = 32; off; off >>= 1) acc += __shfl_xor(acc, off);
    if ((tid & 63) == 0) wsum[tid >> 6] = acc;
    __syncthreads();
    if (tid == 0) {
        double s = 0.0;
        #pragma unroll
        for (int w = 0; w < 7; ++w) s += wsum[w];
        g_part[blk] = -s * (1.0 / (448.0 * 448.0));
    }
}

__global__ void k_final(const int* __restrict__ label, float* __restrict__ out) {
    int tid = threadIdx.x;               // 256
    double s = 0.0;
    for (int i = tid; i < BNUM * CNUM * NTILE; i += 256)
        if (label[i / NTILE] != 0) s += g_part[i];
    #pragma unroll
    for (int off = 32; off; off >>= 1) s += __shfl_xor(s, off);
    __shared__ double wsum[4];
    if ((tid & 63) == 0) wsum[tid >> 6] = s;
    __syncthreads();
    if (tid == 0) {
        int sa = 0;
        for (int i = 0; i < BNUM * CNUM; ++i) sa += (label[i] != 0) ? 1 : 0;
        out[0] = (float)((wsum[0] + wsum[1] + wsum[2] + wsum[3]) / (double)sa);
    }
}

extern "C" void kernel_launch(void* const* d_in, const int* in_sizes, int n_in,
                              void* d_out, int out_size, void* d_ws, size_t ws_size,
                              hipStream_t stream) {
    const float* sm    = (const float*)d_in[0];   // (L,B,N,784)
    const float* score = (const float*)d_in[1];   // (B,N,C)
    const int*   label = (const int*)d_in[2];     // (B,C)
    const int*   gt    = (const int*)d_in[3];     // (B,448,448)
    float* out = (float*)d_out;

    hipLaunchKernelGGL(k_rm,    dim3(BNUM * NNUM),         dim3(256), 0, stream, sm);
    hipLaunchKernelGGL(k_adj,   dim3(BNUM * NNUM),         dim3(320), 0, stream);
    hipLaunchKernelGGL(k_cm,    dim3(BNUM * CNUM),         dim3(256), 0, stream, score, label);
    hipLaunchKernelGGL(k_bce,   dim3(BNUM * CNUM * NTILE), dim3(448), 0, stream, gt, label);
    hipLaunchKernelGGL(k_final, dim3(1),                   dim3(256), 0, stream, label, out);
}